// Round 5
// baseline (1861.128 us; speedup 1.0000x reference)
//
#include <hip/hip_runtime.h>
#include <hip/hip_fp16.h>

constexpr int N_USERS   = 50000;
constexpr int N_ENT     = 100000;
constexpr int N_NODES   = 150000;
constexpr int N_EDGES   = 2400000;
constexpr int OUT_D     = 176;            // 64 + 64 + 32 + 16
constexpr int NB        = 8;              // column blocks (L2 windows)
constexpr int BLKN      = 18750;          // nodes per column block
constexpr int N_BUCKETS = N_NODES * NB;   // 1,200,000
constexpr int SCAN_BLKS = (N_BUCKETS + 1023) / 1024;   // 1172

// ---- workspace layout (bytes) ---------------------------------------------
// persistent: xh @0 (19.2MB) | cols @19.2M (9.6MB) | vals @28.8M (4.8MB) |
//             base @33.6M (0.6MB) | cnt16 @34,200,320 (2.4MB)   = 36.6MB
// temp (before init overwrites xh): cursor32 @0 (4.8MB), bsum @4.8M (4.7KB)

// ---------------------------------------------------------------------------
// init: out[:,0:64) = concat(ue,ee);  xh = fp16 shadow [N][64]
// ---------------------------------------------------------------------------
__global__ __launch_bounds__(256) void init_x_kernel(const float* __restrict__ ue,
                                                     const float* __restrict__ ee,
                                                     float* __restrict__ out,
                                                     __half* __restrict__ xh) {
    int tid = blockIdx.x * 256 + threadIdx.x;    // N_NODES * 16 float4s
    int n = tid >> 4, q = tid & 15;
    const float* src = (n < N_USERS) ? ue + (size_t)n * 64
                                     : ee + (size_t)(n - N_USERS) * 64;
    float4 v = *(const float4*)(src + q * 4);
    *(float4*)(out + (size_t)n * OUT_D + q * 4) = v;
    union { __half2 h[2]; uint2 u; } pk;
    pk.h[0] = __floats2half2_rn(v.x, v.y);
    pk.h[1] = __floats2half2_rn(v.z, v.w);
    *(uint2*)(xh + (size_t)n * 64 + q * 4) = pk.u;
}

// ---------------------------------------------------------------------------
// CSR with key = row*8 + col/18750
// ---------------------------------------------------------------------------
__global__ __launch_bounds__(256) void hist_kernel(const int* __restrict__ er,
                                                   const int* __restrict__ ec,
                                                   int* __restrict__ cnt) {
    int e = blockIdx.x * 256 + threadIdx.x;      // N_EDGES % 256 == 0
    int key = er[e] * NB + ec[e] / BLKN;
    atomicAdd(&cnt[key], 1);
}

// scan phase A: per-1024-block sums of cursor -> bsum[1172]
__global__ __launch_bounds__(1024) void scanA_kernel(const int* __restrict__ cur,
                                                     int* __restrict__ bsum) {
    __shared__ int wsum[16];
    int i = blockIdx.x * 1024 + threadIdx.x;
    int v = (i < N_BUCKETS) ? cur[i] : 0;
    #pragma unroll
    for (int off = 32; off; off >>= 1) v += __shfl_xor(v, off);
    int lane = threadIdx.x & 63, w = threadIdx.x >> 6;
    if (lane == 0) wsum[w] = v;
    __syncthreads();
    if (threadIdx.x == 0) {
        int t = 0;
        #pragma unroll
        for (int k = 0; k < 16; ++k) t += wsum[k];
        bsum[blockIdx.x] = t;
    }
}

// scan phase B: single-block exclusive scan of bsum[SCAN_BLKS] in place
__global__ __launch_bounds__(1024) void scanB_kernel(int* __restrict__ bsum) {
    __shared__ int wtot[16];
    __shared__ int carry_s;
    int tid = threadIdx.x;
    int lane = tid & 63, w = tid >> 6;
    if (tid == 0) carry_s = 0;
    __syncthreads();
    for (int base = 0; base < SCAN_BLKS; base += 1024) {
        int i = base + tid;
        int v = (i < SCAN_BLKS) ? bsum[i] : 0;
        int incl = v;
        #pragma unroll
        for (int off = 1; off < 64; off <<= 1) {
            int t = __shfl_up(incl, off);
            if (lane >= off) incl += t;
        }
        if (lane == 63) wtot[w] = incl;
        __syncthreads();
        int woff = 0, total = 0;
        #pragma unroll
        for (int k = 0; k < 16; ++k) {
            int tk = wtot[k];
            if (k < w) woff += tk;
            total += tk;
        }
        if (i < SCAN_BLKS) bsum[i] = carry_s + woff + incl - v;
        __syncthreads();
        if (tid == 0) carry_s += total;
        __syncthreads();
    }
}

// scan phase C: local exclusive scan + block offset -> cursor[i] global excl.
__global__ __launch_bounds__(1024) void scanC_kernel(int* __restrict__ cur,
                                                     const int* __restrict__ bsum) {
    __shared__ int wtot[16];
    int i = blockIdx.x * 1024 + threadIdx.x;
    int lane = threadIdx.x & 63, w = threadIdx.x >> 6;
    int v = (i < N_BUCKETS) ? cur[i] : 0;
    int incl = v;
    #pragma unroll
    for (int off = 1; off < 64; off <<= 1) {
        int t = __shfl_up(incl, off);
        if (lane >= off) incl += t;
    }
    if (lane == 63) wtot[w] = incl;
    __syncthreads();
    int woff = 0;
    #pragma unroll
    for (int k = 0; k < 16; ++k) if (k < w) woff += wtot[k];
    if (i < N_BUCKETS) cur[i] = bsum[blockIdx.x] + woff + incl - v;
}

__global__ __launch_bounds__(256) void build_csr_kernel(const float* __restrict__ ev,
                                                        const int*   __restrict__ er,
                                                        const int*   __restrict__ ec,
                                                        int*    __restrict__ cursor,
                                                        int*    __restrict__ cols,
                                                        __half* __restrict__ vals) {
    int e = blockIdx.x * 256 + threadIdx.x;      // N_EDGES % 256 == 0
    int key = er[e] * NB + ec[e] / BLKN;
    int pos = atomicAdd(&cursor[key], 1);
    cols[pos] = ec[e];
    vals[pos] = __float2half(ev[e]);
}

// compact: cnt16[k] = bucket count; base[n] = start of node n's first bucket
__global__ __launch_bounds__(256) void compact_kernel(const int* __restrict__ cur,
                                                      int* __restrict__ base,
                                                      unsigned short* __restrict__ cnt16) {
    int k = blockIdx.x * 256 + threadIdx.x;
    if (k >= N_BUCKETS) return;
    int prev = k ? cur[k - 1] : 0;
    cnt16[k] = (unsigned short)(cur[k] - prev);
    if ((k & (NB - 1)) == 0) base[k / NB] = prev;
}

// ---------------------------------------------------------------------------
// Pass kernel: one wave per node; gather only edges in column-block p
// (window = 18750 rows of xh, 2.4MB -> XCD-L2 resident), accumulate into
// fp16 side stored in out columns [cout, cout+DIN/2) (as half2).
// ---------------------------------------------------------------------------
template<int DIN, bool FIRST>
__global__ __launch_bounds__(256, 8) void pass_kernel(
        const int* __restrict__ base,
        const unsigned short* __restrict__ cnt16,
        const int*    __restrict__ cols,
        const __half* __restrict__ vals,
        const __half* __restrict__ xh,
        float* __restrict__ out,
        int p, int cout) {
    int tid = threadIdx.x;
    int w = tid >> 6, lane = tid & 63;
    int n = blockIdx.x * 4 + w;

    constexpr int HP = DIN / 2;         // half2 per row
    constexpr int NE = 128 / DIN;       // edges per wave-gather
    int g = lane / HP;
    int t = lane % HP;

    uint4 cw = *(const uint4*)(cnt16 + (size_t)n * NB);
    int s = base[n], cnt = 0;
    #pragma unroll
    for (int q = 0; q < 8; ++q) {
        unsigned word = (q < 2) ? cw.x : (q < 4) ? cw.y : (q < 6) ? cw.z : cw.w;
        int cq = (q & 1) ? (int)(word >> 16) : (int)(word & 0xffff);
        if (q < p) s += cq;
        if (q == p) cnt = cq;
    }
    if (!FIRST && cnt == 0) return;
    int e_end = s + cnt;

    const __half2* xr = (const __half2*)xh;
    float accx = 0.f, accy = 0.f;
    for (int e = s; e < e_end; e += 2 * NE) {
        int i0 = e + g, i1 = e + NE + g;
        bool k0 = i0 < e_end, k1 = i1 < e_end;
        int   c0 = k0 ? cols[i0] : 0;
        int   c1 = k1 ? cols[i1] : 0;
        float v0 = k0 ? __half2float(vals[i0]) : 0.f;
        float v1 = k1 ? __half2float(vals[i1]) : 0.f;
        float2 f0 = __half22float2(xr[(size_t)c0 * HP + t]);
        float2 f1 = __half22float2(xr[(size_t)c1 * HP + t]);
        accx += v0 * f0.x; accy += v0 * f0.y;
        accx += v1 * f1.x; accy += v1 * f1.y;
    }
    #pragma unroll
    for (int m = 32; m >= HP; m >>= 1) {
        accx += __shfl_xor(accx, m);
        accy += __shfl_xor(accy, m);
    }

    if (lane < HP) {
        __half2* sp = (__half2*)((char*)out + (size_t)n * (OUT_D * 4) + (size_t)cout * 4);
        float2 cur = FIRST ? make_float2(0.f, 0.f) : __half22float2(sp[lane]);
        sp[lane] = __floats2half2_rn(cur.x + accx, cur.y + accy);
    }
}

// ---------------------------------------------------------------------------
// Dense kernel: read side (fp16, in out cols [cout..)) + x (fp32, cols cin),
// a = x+side, b = x*side, h = leaky(a@Wgc+bgc)+leaky(b@Wbi+bbi),
// out[n, cout+o] = h/||h||; optional fp16 shadow write for next layer.
// Weights staged in LDS as fp16 (16KB max -> 8 blocks/CU).
// ---------------------------------------------------------------------------
template<int DIN, int DOUT, bool SHADOW>
__global__ __launch_bounds__(256, 8) void dense_kernel(
        float* __restrict__ out,
        __half* __restrict__ xh,
        const float* __restrict__ Wgc, const float* __restrict__ bgc,
        const float* __restrict__ Wbi, const float* __restrict__ bbi,
        int cin, int cout) {
    __shared__ __half wg[DIN * DOUT];
    __shared__ __half wb[DIN * DOUT];
    __shared__ float as[4][DIN];
    __shared__ float bs[4][DIN];

    int tid = threadIdx.x;
    #pragma unroll
    for (int i = tid; i < DIN * DOUT; i += 256) {
        wg[i] = __float2half(Wgc[i]);
        wb[i] = __float2half(Wbi[i]);
    }

    int w = tid >> 6, lane = tid & 63;
    int n = blockIdx.x * 4 + w;
    constexpr int HP = DIN / 2;

    if (lane < HP) {
        const __half2* sp = (const __half2*)((const char*)out + (size_t)n * (OUT_D * 4) + (size_t)cout * 4);
        float2 sv = __half22float2(sp[lane]);
        float2 xv = *(const float2*)(out + (size_t)n * OUT_D + cin + 2 * lane);
        as[w][2 * lane]     = xv.x + sv.x;
        as[w][2 * lane + 1] = xv.y + sv.y;
        bs[w][2 * lane]     = xv.x * sv.x;
        bs[w][2 * lane + 1] = xv.y * sv.y;
    }
    __syncthreads();

    float h = 0.f;
    if (lane < DOUT) {
        float ag = bgc[lane], ab = bbi[lane];
        #pragma unroll 16
        for (int i = 0; i < DIN; ++i) {
            ag += as[w][i] * __half2float(wg[i * DOUT + lane]);
            ab += bs[w][i] * __half2float(wb[i * DOUT + lane]);
        }
        ag = ag > 0.f ? ag : 0.01f * ag;   // leaky_relu slope 0.01
        ab = ab > 0.f ? ab : 0.01f * ab;
        h = ag + ab;
    }
    float ss = h * h;
    #pragma unroll
    for (int off = 32; off; off >>= 1) ss += __shfl_xor(ss, off);

    if (lane < DOUT) {
        float inv = 1.f / fmaxf(sqrtf(ss), 1e-12f);
        float r = h * inv;
        out[(size_t)n * OUT_D + cout + lane] = r;
        if (SHADOW) xh[(size_t)n * DOUT + lane] = __float2half(r);
    }
}

extern "C" void kernel_launch(void* const* d_in, const int* in_sizes, int n_in,
                              void* d_out, int out_size, void* d_ws, size_t ws_size,
                              hipStream_t stream) {
    const float* ue = (const float*)d_in[0];
    const float* ee = (const float*)d_in[1];
    const float* ev = (const float*)d_in[2];
    const int*   er = (const int*)d_in[3];
    const int*   ec = (const int*)d_in[4];
    float* out = (float*)d_out;

    __half*         xh    = (__half*)d_ws;
    int*            cols  = (int*)((char*)d_ws + 19200000);
    __half*         vals  = (__half*)((char*)d_ws + 28800000);
    int*            base  = (int*)((char*)d_ws + 33600000);
    unsigned short* cnt16 = (unsigned short*)((char*)d_ws + 34200320);
    int*            cursor = (int*)d_ws;                      // temp, over xh
    int*            bsum   = (int*)((char*)d_ws + 4800000);   // temp, over xh

    // ---- CSR build (before init: cursor/bsum overlap xh) ----
    hipMemsetAsync(cursor, 0, (size_t)N_BUCKETS * 4, stream);
    hist_kernel<<<N_EDGES / 256, 256, 0, stream>>>(er, ec, cursor);
    scanA_kernel<<<SCAN_BLKS, 1024, 0, stream>>>(cursor, bsum);
    scanB_kernel<<<1, 1024, 0, stream>>>(bsum);
    scanC_kernel<<<SCAN_BLKS, 1024, 0, stream>>>(cursor, bsum);
    build_csr_kernel<<<N_EDGES / 256, 256, 0, stream>>>(ev, er, ec, cursor, cols, vals);
    compact_kernel<<<(N_BUCKETS + 255) / 256, 256, 0, stream>>>(cursor, base, cnt16);

    init_x_kernel<<<(N_NODES * 16) / 256, 256, 0, stream>>>(ue, ee, out, xh);

    const int GRID = N_NODES / 4;   // 37500

    // ---- layer 0: DIN=64 DOUT=64, x at col 0, side/out at col 64 ----
    pass_kernel<64, true><<<GRID, 256, 0, stream>>>(base, cnt16, cols, vals, xh, out, 0, 64);
    for (int p = 1; p < NB; ++p)
        pass_kernel<64, false><<<GRID, 256, 0, stream>>>(base, cnt16, cols, vals, xh, out, p, 64);
    dense_kernel<64, 64, true><<<GRID, 256, 0, stream>>>(out, xh,
        (const float*)d_in[5], (const float*)d_in[6],
        (const float*)d_in[7], (const float*)d_in[8], 0, 64);

    // ---- layer 1: DIN=64 DOUT=32, x at col 64, side/out at col 128 ----
    pass_kernel<64, true><<<GRID, 256, 0, stream>>>(base, cnt16, cols, vals, xh, out, 0, 128);
    for (int p = 1; p < NB; ++p)
        pass_kernel<64, false><<<GRID, 256, 0, stream>>>(base, cnt16, cols, vals, xh, out, p, 128);
    dense_kernel<64, 32, true><<<GRID, 256, 0, stream>>>(out, xh,
        (const float*)d_in[9], (const float*)d_in[10],
        (const float*)d_in[11], (const float*)d_in[12], 64, 128);

    // ---- layer 2: DIN=32 DOUT=16, x at col 128, side/out at col 160 ----
    pass_kernel<32, true><<<GRID, 256, 0, stream>>>(base, cnt16, cols, vals, xh, out, 0, 160);
    for (int p = 1; p < NB; ++p)
        pass_kernel<32, false><<<GRID, 256, 0, stream>>>(base, cnt16, cols, vals, xh, out, p, 160);
    dense_kernel<32, 16, false><<<GRID, 256, 0, stream>>>(out, xh,
        (const float*)d_in[13], (const float*)d_in[14],
        (const float*)d_in[15], (const float*)d_in[16], 128, 160);
}

// Round 6
// 1018.046 us; speedup vs baseline: 1.8281x; 1.8281x over previous
//
#include <hip/hip_runtime.h>
#include <hip/hip_fp16.h>

constexpr int N_USERS = 50000;
constexpr int N_ENT   = 100000;
constexpr int N_NODES = 150000;
constexpr int N_EDGES = 2400000;
constexpr int OUT_D   = 176;               // 64 + 64 + 32 + 16

// ws layout (bytes): xh fp16 [N][<=64] @0 (19.2MB) |
//                    edges u32 (col<<14 | val14) @19,200,000 (9.6MB) |
//                    cursor int[N] @28,800,000 (0.6MB)          = 29.4MB

// ---------------------------------------------------------------------------
// init: out[:,0:64) = concat(ue,ee);  xh = fp16 shadow [N][64]
// ---------------------------------------------------------------------------
__global__ __launch_bounds__(256) void init_x_kernel(const float* __restrict__ ue,
                                                     const float* __restrict__ ee,
                                                     float* __restrict__ out,
                                                     __half* __restrict__ xh) {
    int tid = blockIdx.x * 256 + threadIdx.x;    // N_NODES * 16 float4s
    int n = tid >> 4, q = tid & 15;
    const float* src = (n < N_USERS) ? ue + (size_t)n * 64
                                     : ee + (size_t)(n - N_USERS) * 64;
    float4 v = *(const float4*)(src + q * 4);
    *(float4*)(out + (size_t)n * OUT_D + q * 4) = v;
    union { __half2 h[2]; uint2 u; } pk;
    pk.h[0] = __floats2half2_rn(v.x, v.y);
    pk.h[1] = __floats2half2_rn(v.z, v.w);
    *(uint2*)(xh + (size_t)n * 64 + q * 4) = pk.u;
}

// fp32 slab column block -> dense fp16 shadow ([N][DIN]); 2 dims per thread
__global__ __launch_bounds__(256) void conv_kernel(const float* __restrict__ src,
                                                   __half* __restrict__ xh, int DIN) {
    int tid = blockIdx.x * 256 + threadIdx.x;    // N_NODES * DIN/2
    int n = tid / (DIN / 2), t = tid % (DIN / 2);
    float2 v = *(const float2*)(src + (size_t)n * OUT_D + 2 * t);
    *(__half2*)(xh + (size_t)n * DIN + 2 * t) = __floats2half2_rn(v.x, v.y);
}

// ---------------------------------------------------------------------------
// CSR: histogram -> in-place exclusive scan -> counting sort.
// After build: cursor[n] == end of row n;  start = n ? cursor[n-1] : 0.
// ---------------------------------------------------------------------------
__global__ __launch_bounds__(256) void hist_kernel(const int* __restrict__ er,
                                                   int* __restrict__ cnt) {
    int e = blockIdx.x * 256 + threadIdx.x;      // N_EDGES % 256 == 0
    atomicAdd(&cnt[er[e]], 1);
}

__global__ __launch_bounds__(1024) void scan_kernel(int* __restrict__ cursor) {
    __shared__ int wtot[16];
    __shared__ int carry_s;
    int tid = threadIdx.x;
    int lane = tid & 63, w = tid >> 6;
    if (tid == 0) carry_s = 0;
    __syncthreads();
    for (int base = 0; base < N_NODES; base += 1024) {
        int i = base + tid;
        int v = (i < N_NODES) ? cursor[i] : 0;
        int incl = v;
        #pragma unroll
        for (int off = 1; off < 64; off <<= 1) {
            int t = __shfl_up(incl, off);
            if (lane >= off) incl += t;
        }
        if (lane == 63) wtot[w] = incl;
        __syncthreads();
        int woff = 0, total = 0;
        #pragma unroll
        for (int k = 0; k < 16; ++k) {
            int tk = wtot[k];
            if (k < w) woff += tk;
            total += tk;
        }
        if (i < N_NODES) cursor[i] = carry_s + woff + incl - v;  // exclusive
        __syncthreads();
        if (tid == 0) carry_s += total;
        __syncthreads();
    }
}

__global__ __launch_bounds__(256) void build_csr_kernel(const float* __restrict__ ev,
                                                        const int*   __restrict__ er,
                                                        const int*   __restrict__ ec,
                                                        int*          __restrict__ cursor,
                                                        unsigned int* __restrict__ edges) {
    int e = blockIdx.x * 256 + threadIdx.x;      // N_EDGES % 256 == 0
    int pos = atomicAdd(&cursor[er[e]], 1);
    int v14 = (int)(ev[e] * 16384.0f + 0.5f);
    v14 = v14 > 16383 ? 16383 : v14;
    edges[pos] = ((unsigned int)ec[e] << 14) | (unsigned int)v14;
}

// ---------------------------------------------------------------------------
// Fused layer. One wave per node. 8-deep predicated gather pipeline:
// per round, 8 edge-record loads then 8 row-gathers in flight (NE edges per
// gather instr). val = 14-bit fixed point, col = bits [14..31].
// Then a = x+side, b = x*side, dense (weights via L1), leaky, sum, L2-norm.
// ---------------------------------------------------------------------------
template<int DIN, int DOUT>
__global__ __launch_bounds__(256, 4) void fused_layer_kernel(
        const int*          __restrict__ cursor,
        const unsigned int* __restrict__ edges,
        const __half*       __restrict__ xh,
        float* __restrict__ out,
        const float* __restrict__ Wgc, const float* __restrict__ bgc,
        const float* __restrict__ Wbi, const float* __restrict__ bbi,
        int cin, int cout) {
    __shared__ float as[4][DIN];
    __shared__ float bs[4][DIN];

    int tid = threadIdx.x;
    int w = tid >> 6, lane = tid & 63;
    int n = blockIdx.x * 4 + w;

    constexpr int HP = DIN / 2;         // half2 per row
    constexpr int NE = 128 / DIN;       // edges per wave-gather (2 or 4)
    int g = lane / HP;                  // edge slot within gather instr
    int t = lane % HP;                  // dim-pair index

    int s = n ? cursor[n - 1] : 0;
    int e_end = cursor[n];

    const __half2* xr = (const __half2*)xh;
    float accx = 0.f, accy = 0.f;

    for (int e = s; e < e_end; e += 8 * NE) {
        unsigned int ue[8];
        #pragma unroll
        for (int j = 0; j < 8; ++j) {
            int i = e + j * NE + g;
            // unguarded load (lands in ws; edges+2.4M+16 < ws end), then select
            unsigned int raw = edges[i];
            ue[j] = (i < e_end) ? raw : 0u;
        }
        float vx[8], vy[8], vv[8];
        #pragma unroll
        for (int j = 0; j < 8; ++j) {
            unsigned int c = ue[j] >> 14;
            vv[j] = (float)(ue[j] & 16383u) * (1.0f / 16384.0f);
            unsigned int off = c * HP + t;
            unsigned int raw = __builtin_nontemporal_load((const unsigned int*)(xr + off));
            __half2 h2 = *(__half2*)&raw;
            float2 f = __half22float2(h2);
            vx[j] = f.x; vy[j] = f.y;
        }
        #pragma unroll
        for (int j = 0; j < 8; ++j) {
            accx += vv[j] * vx[j];
            accy += vv[j] * vy[j];
        }
    }
    // fold edge slots down to lanes 0..HP-1
    #pragma unroll
    for (int m = 32; m >= HP; m >>= 1) {
        accx += __shfl_xor(accx, m);
        accy += __shfl_xor(accy, m);
    }

    if (lane < HP) {
        float2 xv = *(const float2*)(out + (size_t)n * OUT_D + cin + 2 * lane);
        as[w][2 * lane]     = xv.x + accx;
        as[w][2 * lane + 1] = xv.y + accy;
        bs[w][2 * lane]     = xv.x * accx;
        bs[w][2 * lane + 1] = xv.y * accy;
    }
    __syncthreads();

    float h = 0.f;
    if (lane < DOUT) {
        float ag = bgc[lane], ab = bbi[lane];
        #pragma unroll 16
        for (int i = 0; i < DIN; ++i) {
            ag += as[w][i] * Wgc[i * DOUT + lane];
            ab += bs[w][i] * Wbi[i * DOUT + lane];
        }
        ag = ag > 0.f ? ag : 0.01f * ag;   // leaky_relu slope 0.01
        ab = ab > 0.f ? ab : 0.01f * ab;
        h = ag + ab;
    }
    float ss = h * h;
    #pragma unroll
    for (int off = 32; off; off >>= 1) ss += __shfl_xor(ss, off);

    if (lane < DOUT) {
        float inv = 1.f / fmaxf(sqrtf(ss), 1e-12f);
        out[(size_t)n * OUT_D + cout + lane] = h * inv;
    }
}

extern "C" void kernel_launch(void* const* d_in, const int* in_sizes, int n_in,
                              void* d_out, int out_size, void* d_ws, size_t ws_size,
                              hipStream_t stream) {
    const float* ue = (const float*)d_in[0];
    const float* ee = (const float*)d_in[1];
    const float* ev = (const float*)d_in[2];
    const int*   er = (const int*)d_in[3];
    const int*   ec = (const int*)d_in[4];
    float* out = (float*)d_out;

    __half*       xh     = (__half*)d_ws;
    unsigned int* edges  = (unsigned int*)((char*)d_ws + 19200000);
    int*          cursor = (int*)((char*)d_ws + 28800000);

    hipMemsetAsync(cursor, 0, (size_t)N_NODES * sizeof(int), stream);
    hist_kernel<<<N_EDGES / 256, 256, 0, stream>>>(er, cursor);
    scan_kernel<<<1, 1024, 0, stream>>>(cursor);
    build_csr_kernel<<<N_EDGES / 256, 256, 0, stream>>>(ev, er, ec, cursor, edges);

    init_x_kernel<<<(N_NODES * 16) / 256, 256, 0, stream>>>(ue, ee, out, xh);

    const int GRID = N_NODES / 4;   // 37500

    // layer 0: DIN=64 DOUT=64, x at col 0, write col 64
    fused_layer_kernel<64, 64><<<GRID, 256, 0, stream>>>(cursor, edges, xh, out,
        (const float*)d_in[5], (const float*)d_in[6],
        (const float*)d_in[7], (const float*)d_in[8], 0, 64);
    conv_kernel<<<(N_NODES * 32) / 256, 256, 0, stream>>>(out + 64, xh, 64);

    // layer 1: DIN=64 DOUT=32, x at col 64, write col 128
    fused_layer_kernel<64, 32><<<GRID, 256, 0, stream>>>(cursor, edges, xh, out,
        (const float*)d_in[9], (const float*)d_in[10],
        (const float*)d_in[11], (const float*)d_in[12], 64, 128);
    conv_kernel<<<(N_NODES * 16) / 256, 256, 0, stream>>>(out + 128, xh, 32);

    // layer 2: DIN=32 DOUT=16, x at col 128, write col 160
    fused_layer_kernel<32, 16><<<GRID, 256, 0, stream>>>(cursor, edges, xh, out,
        (const float*)d_in[13], (const float*)d_in[14],
        (const float*)d_in[15], (const float*)d_in[16], 128, 160);
}

// Round 7
// 994.425 us; speedup vs baseline: 1.8716x; 1.0238x over previous
//
#include <hip/hip_runtime.h>
#include <hip/hip_fp16.h>

constexpr int N_USERS = 50000;
constexpr int N_ENT   = 100000;
constexpr int N_NODES = 150000;
constexpr int N_EDGES = 2400000;
constexpr int OUT_D   = 176;               // 64 + 64 + 32 + 16

// ws layout (bytes): xh fp16 [N][<=64] @0 (19.2MB) |
//   edges u32 (col<<14 | val14) @19,200,000 (9.6MB) |
//   cursor int[N] @28,800,000 (0.6MB) |
//   WT __half[13312] @29,400,000 (26.6KB)            = ~29.43MB

typedef _Float16 h2v __attribute__((ext_vector_type(2)));
union H2U { unsigned u; h2v v; };

__device__ inline float dot2(unsigned a, unsigned b, float c) {
    H2U x, y; x.u = a; y.u = b;
    return __builtin_amdgcn_fdot2(x.v, y.v, c, false);
}

// ---------------------------------------------------------------------------
// init: out[:,0:64) = concat(ue,ee);  xh = fp16 shadow [N][64]
// ---------------------------------------------------------------------------
__global__ __launch_bounds__(256) void init_x_kernel(const float* __restrict__ ue,
                                                     const float* __restrict__ ee,
                                                     float* __restrict__ out,
                                                     __half* __restrict__ xh) {
    int tid = blockIdx.x * 256 + threadIdx.x;    // N_NODES * 16 float4s
    int n = tid >> 4, q = tid & 15;
    const float* src = (n < N_USERS) ? ue + (size_t)n * 64
                                     : ee + (size_t)(n - N_USERS) * 64;
    float4 v = *(const float4*)(src + q * 4);
    *(float4*)(out + (size_t)n * OUT_D + q * 4) = v;
    union { __half2 h[2]; uint2 u; } pk;
    pk.h[0] = __floats2half2_rn(v.x, v.y);
    pk.h[1] = __floats2half2_rn(v.z, v.w);
    *(uint2*)(xh + (size_t)n * 64 + q * 4) = pk.u;
}

// fp32 slab column block -> dense fp16 shadow ([N][DIN]); 2 dims per thread
__global__ __launch_bounds__(256) void conv_kernel(const float* __restrict__ src,
                                                   __half* __restrict__ xh, int DIN) {
    int tid = blockIdx.x * 256 + threadIdx.x;    // N_NODES * DIN/2
    int n = tid / (DIN / 2), t = tid % (DIN / 2);
    float2 v = *(const float2*)(src + (size_t)n * OUT_D + 2 * t);
    *(__half2*)(xh + (size_t)n * DIN + 2 * t) = __floats2half2_rn(v.x, v.y);
}

// ---------------------------------------------------------------------------
// Transposed fp16 weights, all 6 matrices in one flat WT buffer (halves):
//  [0,4096) wg0T 64x64 | [4096,8192) wb0T | [8192,10240) wg1T (o<32,i<64) |
//  [10240,12288) wb1T | [12288,12800) wg2T (o<16,i<32) | [12800,13312) wb2T
//  WT[base + o*DIN + i] = W[i*DOUT + o]
// ---------------------------------------------------------------------------
__global__ __launch_bounds__(256) void wt_kernel(const float* __restrict__ Wg0,
                                                 const float* __restrict__ Wb0,
                                                 const float* __restrict__ Wg1,
                                                 const float* __restrict__ Wb1,
                                                 const float* __restrict__ Wg2,
                                                 const float* __restrict__ Wb2,
                                                 __half* __restrict__ WT) {
    int idx = blockIdx.x * 256 + threadIdx.x;   // 52*256 == 13312
    const float* src; int din, dout, base;
    if (idx < 8192)       { base = (idx < 4096) ? 0 : 4096;
                            src  = (idx < 4096) ? Wg0 : Wb0;  din = 64; dout = 64; }
    else if (idx < 12288) { base = (idx < 10240) ? 8192 : 10240;
                            src  = (idx < 10240) ? Wg1 : Wb1; din = 64; dout = 32; }
    else                  { base = (idx < 12800) ? 12288 : 12800;
                            src  = (idx < 12800) ? Wg2 : Wb2; din = 32; dout = 16; }
    int r = idx - base;
    int o = r / din, i = r % din;
    WT[idx] = __float2half(src[i * dout + o]);
}

// ---------------------------------------------------------------------------
// CSR: histogram -> in-place exclusive scan -> counting sort.
// ---------------------------------------------------------------------------
__global__ __launch_bounds__(256) void hist_kernel(const int* __restrict__ er,
                                                   int* __restrict__ cnt) {
    int e = blockIdx.x * 256 + threadIdx.x;      // N_EDGES % 256 == 0
    atomicAdd(&cnt[er[e]], 1);
}

__global__ __launch_bounds__(1024) void scan_kernel(int* __restrict__ cursor) {
    __shared__ int wtot[16];
    __shared__ int carry_s;
    int tid = threadIdx.x;
    int lane = tid & 63, w = tid >> 6;
    if (tid == 0) carry_s = 0;
    __syncthreads();
    for (int base = 0; base < N_NODES; base += 1024) {
        int i = base + tid;
        int v = (i < N_NODES) ? cursor[i] : 0;
        int incl = v;
        #pragma unroll
        for (int off = 1; off < 64; off <<= 1) {
            int t = __shfl_up(incl, off);
            if (lane >= off) incl += t;
        }
        if (lane == 63) wtot[w] = incl;
        __syncthreads();
        int woff = 0, total = 0;
        #pragma unroll
        for (int k = 0; k < 16; ++k) {
            int tk = wtot[k];
            if (k < w) woff += tk;
            total += tk;
        }
        if (i < N_NODES) cursor[i] = carry_s + woff + incl - v;  // exclusive
        __syncthreads();
        if (tid == 0) carry_s += total;
        __syncthreads();
    }
}

__global__ __launch_bounds__(256) void build_csr_kernel(const float* __restrict__ ev,
                                                        const int*   __restrict__ er,
                                                        const int*   __restrict__ ec,
                                                        int*          __restrict__ cursor,
                                                        unsigned int* __restrict__ edges) {
    int e = blockIdx.x * 256 + threadIdx.x;      // N_EDGES % 256 == 0
    int pos = atomicAdd(&cursor[er[e]], 1);
    int v14 = (int)(ev[e] * 16384.0f + 0.5f);
    v14 = v14 > 16383 ? 16383 : v14;
    edges[pos] = ((unsigned int)ec[e] << 14) | (unsigned int)v14;
}

// ---------------------------------------------------------------------------
// Fused layer. One wave per node.
// Gather: per round, ONE edge-record load (edges[e+lane]) + 8 shuffles +
// 8 predicated row-gathers in flight (NE edges per gather instr).
// Dense: half2 as/bs in LDS; transposed fp16 weights from global (L1-hot);
// v_dot2_f32_f16 accumulation. For DOUT==DIN/2, half-wave gc/bi split.
// ---------------------------------------------------------------------------
template<int DIN, int DOUT>
__global__ __launch_bounds__(256, 4) void fused_layer_kernel(
        const int*          __restrict__ cursor,
        const unsigned int* __restrict__ edges,
        const __half*       __restrict__ xh,
        float* __restrict__ out,
        const __half* __restrict__ WT, int wgOff, int wbOff,
        const float* __restrict__ bgc, const float* __restrict__ bbi,
        int cin, int cout) {
    __shared__ unsigned ash[4][DIN / 2];
    __shared__ unsigned bsh[4][DIN / 2];

    int tid = threadIdx.x;
    int w = tid >> 6, lane = tid & 63;
    int n = blockIdx.x * 4 + w;

    constexpr int HP = DIN / 2;         // half2 per row
    constexpr int NE = 128 / DIN;       // edges per wave-gather (2 or 4)
    int g = lane / HP;                  // edge slot within gather instr
    int t = lane % HP;                  // dim-pair index

    int s = n ? cursor[n - 1] : 0;
    int e_end = cursor[n];

    const __half2* xr = (const __half2*)xh;
    float accx = 0.f, accy = 0.f;

    for (int e = s; e < e_end; e += 8 * NE) {
        unsigned raw = edges[e + lane];          // one load covers the round
        unsigned ue[8];
        #pragma unroll
        for (int j = 0; j < 8; ++j) {
            unsigned r2 = __shfl(raw, j * NE + g);
            ue[j] = (e + j * NE + g < e_end) ? r2 : 0u;
        }
        float vv[8]; float2 f[8];
        #pragma unroll
        for (int j = 0; j < 8; ++j) {
            unsigned c = ue[j] >> 14;
            vv[j] = (float)(ue[j] & 16383u) * (1.0f / 16384.0f);
            f[j] = __half22float2(xr[(size_t)c * HP + t]);
        }
        #pragma unroll
        for (int j = 0; j < 8; ++j) {
            accx += vv[j] * f[j].x;
            accy += vv[j] * f[j].y;
        }
    }
    // fold edge slots down to lanes 0..HP-1
    #pragma unroll
    for (int m = 32; m >= HP; m >>= 1) {
        accx += __shfl_xor(accx, m);
        accy += __shfl_xor(accy, m);
    }

    if (lane < HP) {
        float2 xv = *(const float2*)(out + (size_t)n * OUT_D + cin + 2 * lane);
        __half2 a2 = __floats2half2_rn(xv.x + accx, xv.y + accy);
        __half2 b2 = __floats2half2_rn(xv.x * accx, xv.y * accy);
        ash[w][lane] = *(unsigned*)&a2;
        bsh[w][lane] = *(unsigned*)&b2;
    }
    __syncthreads();

    float hres = 0.f;
    if constexpr (DOUT == DIN) {
        int o = lane;
        const __half* wg = WT + wgOff + o * DIN;
        const __half* wb = WT + wbOff + o * DIN;
        float ag = bgc[o], ab = bbi[o];
        #pragma unroll
        for (int k = 0; k < DIN / 8; ++k) {
            uint4 w4g = *(const uint4*)(wg + k * 8);
            uint4 w4b = *(const uint4*)(wb + k * 8);
            uint4 a4  = *(const uint4*)&ash[w][k * 4];
            uint4 b4  = *(const uint4*)&bsh[w][k * 4];
            ag = dot2(a4.x, w4g.x, ag); ag = dot2(a4.y, w4g.y, ag);
            ag = dot2(a4.z, w4g.z, ag); ag = dot2(a4.w, w4g.w, ag);
            ab = dot2(b4.x, w4b.x, ab); ab = dot2(b4.y, w4b.y, ab);
            ab = dot2(b4.z, w4b.z, ab); ab = dot2(b4.w, w4b.w, ab);
        }
        ag = ag > 0.f ? ag : 0.01f * ag;
        ab = ab > 0.f ? ab : 0.01f * ab;
        hres = ag + ab;
    } else {
        // DOUT == DIN/2: lanes [0,DOUT) gc path, [DOUT,2*DOUT) bi path
        int o = lane & (DOUT - 1);
        bool gc = (lane / DOUT) == 0;
        bool active = lane < 2 * DOUT;
        float own = 0.f;
        if (active) {
            const __half*   wp = WT + (gc ? wgOff : wbOff) + o * DIN;
            const unsigned* sp = gc ? &ash[w][0] : &bsh[w][0];
            own = gc ? bgc[o] : bbi[o];
            #pragma unroll
            for (int k = 0; k < DIN / 8; ++k) {
                uint4 w4 = *(const uint4*)(wp + k * 8);
                uint4 s4 = *(const uint4*)(sp + k * 4);
                own = dot2(s4.x, w4.x, own); own = dot2(s4.y, w4.y, own);
                own = dot2(s4.z, w4.z, own); own = dot2(s4.w, w4.w, own);
            }
            own = own > 0.f ? own : 0.01f * own;
        }
        float other = __shfl_xor(own, DOUT);
        hres = active ? own + other : 0.f;
    }

    float hq = (lane < DOUT) ? hres : 0.f;
    float ss = hq * hq;
    #pragma unroll
    for (int off = 32; off; off >>= 1) ss += __shfl_xor(ss, off);

    if (lane < DOUT) {
        float inv = 1.f / fmaxf(sqrtf(ss), 1e-12f);
        out[(size_t)n * OUT_D + cout + lane] = hres * inv;
    }
}

extern "C" void kernel_launch(void* const* d_in, const int* in_sizes, int n_in,
                              void* d_out, int out_size, void* d_ws, size_t ws_size,
                              hipStream_t stream) {
    const float* ue = (const float*)d_in[0];
    const float* ee = (const float*)d_in[1];
    const float* ev = (const float*)d_in[2];
    const int*   er = (const int*)d_in[3];
    const int*   ec = (const int*)d_in[4];
    float* out = (float*)d_out;

    __half*       xh     = (__half*)d_ws;
    unsigned int* edges  = (unsigned int*)((char*)d_ws + 19200000);
    int*          cursor = (int*)((char*)d_ws + 28800000);
    __half*       WT     = (__half*)((char*)d_ws + 29400000);

    hipMemsetAsync(cursor, 0, (size_t)N_NODES * sizeof(int), stream);
    hist_kernel<<<N_EDGES / 256, 256, 0, stream>>>(er, cursor);
    scan_kernel<<<1, 1024, 0, stream>>>(cursor);
    build_csr_kernel<<<N_EDGES / 256, 256, 0, stream>>>(ev, er, ec, cursor, edges);

    init_x_kernel<<<(N_NODES * 16) / 256, 256, 0, stream>>>(ue, ee, out, xh);
    wt_kernel<<<52, 256, 0, stream>>>((const float*)d_in[5],  (const float*)d_in[7],
                                      (const float*)d_in[9],  (const float*)d_in[11],
                                      (const float*)d_in[13], (const float*)d_in[15], WT);

    const int GRID = N_NODES / 4;   // 37500

    // layer 0: DIN=64 DOUT=64, x at col 0, write col 64
    fused_layer_kernel<64, 64><<<GRID, 256, 0, stream>>>(cursor, edges, xh, out,
        WT, 0, 4096, (const float*)d_in[6], (const float*)d_in[8], 0, 64);
    conv_kernel<<<(N_NODES * 32) / 256, 256, 0, stream>>>(out + 64, xh, 64);

    // layer 1: DIN=64 DOUT=32, x at col 64, write col 128
    fused_layer_kernel<64, 32><<<GRID, 256, 0, stream>>>(cursor, edges, xh, out,
        WT, 8192, 10240, (const float*)d_in[10], (const float*)d_in[12], 64, 128);
    conv_kernel<<<(N_NODES * 16) / 256, 256, 0, stream>>>(out + 128, xh, 32);

    // layer 2: DIN=32 DOUT=16, x at col 128, write col 160
    fused_layer_kernel<32, 16><<<GRID, 256, 0, stream>>>(cursor, edges, xh, out,
        WT, 12288, 12800, (const float*)d_in[14], (const float*)d_in[16], 128, 160);
}

// Round 8
// 727.021 us; speedup vs baseline: 2.5599x; 1.3678x over previous
//
#include <hip/hip_runtime.h>
#include <hip/hip_fp16.h>

constexpr int N_USERS = 50000;
constexpr int N_ENT   = 100000;
constexpr int N_NODES = 150000;
constexpr int N_EDGES = 2400000;
constexpr int OUT_D   = 176;               // 64 + 64 + 32 + 16

// ws layout (bytes): xh fp16 [N][<=64] @0 (19.2MB) |
//   edges u32 (col<<14 | val14) @19,200,000 (9.6MB) |
//   cursor int[N] @28,800,000 (0.6MB) |
//   WT __half[13312] @29,400,000 (26.6KB)            = ~29.43MB

typedef _Float16 h2v __attribute__((ext_vector_type(2)));
union H2U { unsigned u; h2v v; };

__device__ inline float dot2(unsigned a, unsigned b, float c) {
    H2U x, y; x.u = a; y.u = b;
    return __builtin_amdgcn_fdot2(x.v, y.v, c, false);
}

// ---------------------------------------------------------------------------
// init: out[:,0:64) = concat(ue,ee);  xh = fp16 shadow [N][64]
// ---------------------------------------------------------------------------
__global__ __launch_bounds__(256) void init_x_kernel(const float* __restrict__ ue,
                                                     const float* __restrict__ ee,
                                                     float* __restrict__ out,
                                                     __half* __restrict__ xh) {
    int tid = blockIdx.x * 256 + threadIdx.x;    // N_NODES * 16 float4s
    int n = tid >> 4, q = tid & 15;
    const float* src = (n < N_USERS) ? ue + (size_t)n * 64
                                     : ee + (size_t)(n - N_USERS) * 64;
    float4 v = *(const float4*)(src + q * 4);
    *(float4*)(out + (size_t)n * OUT_D + q * 4) = v;
    union { __half2 h[2]; uint2 u; } pk;
    pk.h[0] = __floats2half2_rn(v.x, v.y);
    pk.h[1] = __floats2half2_rn(v.z, v.w);
    *(uint2*)(xh + (size_t)n * 64 + q * 4) = pk.u;
}

// fp32 slab column block -> dense fp16 shadow ([N][DIN]); 2 dims per thread
__global__ __launch_bounds__(256) void conv_kernel(const float* __restrict__ src,
                                                   __half* __restrict__ xh, int DIN) {
    int tid = blockIdx.x * 256 + threadIdx.x;    // N_NODES * DIN/2
    int n = tid / (DIN / 2), t = tid % (DIN / 2);
    float2 v = *(const float2*)(src + (size_t)n * OUT_D + 2 * t);
    *(__half2*)(xh + (size_t)n * DIN + 2 * t) = __floats2half2_rn(v.x, v.y);
}

// ---------------------------------------------------------------------------
// Weights, fp16, k-interleaved for coalesced per-o uint4 reads:
//   dest[base + (i/8)*DOUT*8 + o*8 + (i%8)] = W[i*DOUT + o]
// bases (halves): wg0 0 | wb0 4096 | wg1 8192 | wb1 10240 | wg2 12288 | wb2 12800
// ---------------------------------------------------------------------------
__global__ __launch_bounds__(256) void wt_kernel(const float* __restrict__ Wg0,
                                                 const float* __restrict__ Wb0,
                                                 const float* __restrict__ Wg1,
                                                 const float* __restrict__ Wb1,
                                                 const float* __restrict__ Wg2,
                                                 const float* __restrict__ Wb2,
                                                 __half* __restrict__ WT) {
    int idx = blockIdx.x * 256 + threadIdx.x;   // 52*256 == 13312
    const float* src; int dout, base;
    if (idx < 8192)       { base = (idx < 4096) ? 0 : 4096;
                            src  = (idx < 4096) ? Wg0 : Wb0;  dout = 64; }
    else if (idx < 12288) { base = (idx < 10240) ? 8192 : 10240;
                            src  = (idx < 10240) ? Wg1 : Wb1; dout = 32; }
    else                  { base = (idx < 12800) ? 12288 : 12800;
                            src  = (idx < 12800) ? Wg2 : Wb2; dout = 16; }
    int r = idx - base;
    int i = r / dout, o = r % dout;
    int dest = base + (i / 8) * dout * 8 + o * 8 + (i % 8);
    WT[dest] = __float2half(src[r]);
}

// ---------------------------------------------------------------------------
// CSR: histogram -> in-place exclusive scan -> counting sort.
// ---------------------------------------------------------------------------
__global__ __launch_bounds__(256) void hist_kernel(const int* __restrict__ er,
                                                   int* __restrict__ cnt) {
    int e = blockIdx.x * 256 + threadIdx.x;      // N_EDGES % 256 == 0
    atomicAdd(&cnt[er[e]], 1);
}

__global__ __launch_bounds__(1024) void scan_kernel(int* __restrict__ cursor) {
    __shared__ int wtot[16];
    __shared__ int carry_s;
    int tid = threadIdx.x;
    int lane = tid & 63, w = tid >> 6;
    if (tid == 0) carry_s = 0;
    __syncthreads();
    for (int base = 0; base < N_NODES; base += 1024) {
        int i = base + tid;
        int v = (i < N_NODES) ? cursor[i] : 0;
        int incl = v;
        #pragma unroll
        for (int off = 1; off < 64; off <<= 1) {
            int t = __shfl_up(incl, off);
            if (lane >= off) incl += t;
        }
        if (lane == 63) wtot[w] = incl;
        __syncthreads();
        int woff = 0, total = 0;
        #pragma unroll
        for (int k = 0; k < 16; ++k) {
            int tk = wtot[k];
            if (k < w) woff += tk;
            total += tk;
        }
        if (i < N_NODES) cursor[i] = carry_s + woff + incl - v;  // exclusive
        __syncthreads();
        if (tid == 0) carry_s += total;
        __syncthreads();
    }
}

__global__ __launch_bounds__(256) void build_csr_kernel(const float* __restrict__ ev,
                                                        const int*   __restrict__ er,
                                                        const int*   __restrict__ ec,
                                                        int*          __restrict__ cursor,
                                                        unsigned int* __restrict__ edges) {
    int e = blockIdx.x * 256 + threadIdx.x;      // N_EDGES % 256 == 0
    int pos = atomicAdd(&cursor[er[e]], 1);
    int v14 = (int)(ev[e] * 16384.0f + 0.5f);
    v14 = v14 > 16383 ? 16383 : v14;
    edges[pos] = ((unsigned int)ec[e] << 14) | (unsigned int)v14;
}

// ---------------------------------------------------------------------------
// Fused layer. One wave per node.
// Gather: 8 independent predicated edge loads + 8 row-gathers in flight.
// Dense: fp16 weights (k-interleaved, coalesced) hoisted to registers,
// as/bs half2 in LDS (broadcast reads), v_dot2_f32_f16 accumulate.
// DOUT==DIN/2 layers: half-wave gc/bi split.
// ---------------------------------------------------------------------------
template<int DIN, int DOUT>
__global__ __launch_bounds__(256, 4) void fused_layer_kernel(
        const int*          __restrict__ cursor,
        const unsigned int* __restrict__ edges,
        const __half*       __restrict__ xh,
        float* __restrict__ out,
        const __half* __restrict__ WT, int wgOff, int wbOff,
        const float* __restrict__ bgc, const float* __restrict__ bbi,
        int cin, int cout) {
    __shared__ unsigned ash[4][DIN / 2];
    __shared__ unsigned bsh[4][DIN / 2];

    int tid = threadIdx.x;
    int w = tid >> 6, lane = tid & 63;
    int n = blockIdx.x * 4 + w;

    constexpr int HP = DIN / 2;         // half2 per row
    constexpr int NE = 128 / DIN;       // edges per wave-gather (2 or 4)
    int g = lane / HP;                  // edge slot within gather instr
    int t = lane % HP;                  // dim-pair index

    int s = n ? cursor[n - 1] : 0;
    int e_end = cursor[n];

    // hoist x read (guarded; overlaps with gather latency)
    float2 xv = make_float2(0.f, 0.f);
    if (lane < HP) xv = *(const float2*)(out + (size_t)n * OUT_D + cin + 2 * lane);

    const __half2* xr = (const __half2*)xh;
    float accx = 0.f, accy = 0.f;

    for (int e = s; e < e_end; e += 8 * NE) {
        unsigned ue[8];
        #pragma unroll
        for (int j = 0; j < 8; ++j) {
            int i = e + j * NE + g;
            unsigned raw = edges[i];     // unguarded: lands in ws (cursor area)
            ue[j] = (i < e_end) ? raw : 0u;
        }
        float vv[8]; float2 f[8];
        #pragma unroll
        for (int j = 0; j < 8; ++j) {
            unsigned c = ue[j] >> 14;
            vv[j] = (float)(ue[j] & 16383u) * (1.0f / 16384.0f);
            f[j] = __half22float2(xr[(size_t)c * HP + t]);
        }
        #pragma unroll
        for (int j = 0; j < 8; ++j) {
            accx += vv[j] * f[j].x;
            accy += vv[j] * f[j].y;
        }
    }
    // fold edge slots down to lanes 0..HP-1
    #pragma unroll
    for (int m = 32; m >= HP; m >>= 1) {
        accx += __shfl_xor(accx, m);
        accy += __shfl_xor(accy, m);
    }

    if (lane < HP) {
        __half2 a2 = __floats2half2_rn(xv.x + accx, xv.y + accy);
        __half2 b2 = __floats2half2_rn(xv.x * accx, xv.y * accy);
        ash[w][lane] = *(unsigned*)&a2;
        bsh[w][lane] = *(unsigned*)&b2;
    }
    __syncthreads();

    float hres = 0.f;
    if constexpr (DOUT == DIN) {
        int o = lane;
        uint4 wg[DIN / 8], wb[DIN / 8];
        #pragma unroll
        for (int k = 0; k < DIN / 8; ++k) {
            wg[k] = *(const uint4*)(WT + wgOff + (size_t)(k * DOUT + o) * 8);
            wb[k] = *(const uint4*)(WT + wbOff + (size_t)(k * DOUT + o) * 8);
        }
        float ag = bgc[o], ab = bbi[o];
        #pragma unroll
        for (int k = 0; k < DIN / 8; ++k) {
            uint4 a4 = *(const uint4*)&ash[w][k * 4];
            uint4 b4 = *(const uint4*)&bsh[w][k * 4];
            ag = dot2(a4.x, wg[k].x, ag); ag = dot2(a4.y, wg[k].y, ag);
            ag = dot2(a4.z, wg[k].z, ag); ag = dot2(a4.w, wg[k].w, ag);
            ab = dot2(b4.x, wb[k].x, ab); ab = dot2(b4.y, wb[k].y, ab);
            ab = dot2(b4.z, wb[k].z, ab); ab = dot2(b4.w, wb[k].w, ab);
        }
        ag = ag > 0.f ? ag : 0.01f * ag;
        ab = ab > 0.f ? ab : 0.01f * ab;
        hres = ag + ab;
    } else {
        // DOUT == DIN/2: lanes [0,DOUT) gc path, [DOUT,2*DOUT) bi path
        int o = lane & (DOUT - 1);
        bool gc = lane < DOUT;
        bool active = lane < 2 * DOUT;
        int woff2 = gc ? wgOff : wbOff;
        uint4 wr[DIN / 8];
        #pragma unroll
        for (int k = 0; k < DIN / 8; ++k)
            wr[k] = *(const uint4*)(WT + woff2 + (size_t)(k * DOUT + o) * 8);
        const unsigned* sp = gc ? &ash[w][0] : &bsh[w][0];
        float own = active ? (gc ? bgc[o] : bbi[o]) : 0.f;
        #pragma unroll
        for (int k = 0; k < DIN / 8; ++k) {
            uint4 s4 = *(const uint4*)(sp + k * 4);
            own = dot2(s4.x, wr[k].x, own); own = dot2(s4.y, wr[k].y, own);
            own = dot2(s4.z, wr[k].z, own); own = dot2(s4.w, wr[k].w, own);
        }
        own = own > 0.f ? own : 0.01f * own;
        float other = __shfl_xor(own, DOUT);
        hres = own + other;
    }

    float hq = (lane < DOUT) ? hres : 0.f;
    float ss = hq * hq;
    #pragma unroll
    for (int off = 32; off; off >>= 1) ss += __shfl_xor(ss, off);

    if (lane < DOUT) {
        float inv = 1.f / fmaxf(sqrtf(ss), 1e-12f);
        out[(size_t)n * OUT_D + cout + lane] = hres * inv;
    }
}

extern "C" void kernel_launch(void* const* d_in, const int* in_sizes, int n_in,
                              void* d_out, int out_size, void* d_ws, size_t ws_size,
                              hipStream_t stream) {
    const float* ue = (const float*)d_in[0];
    const float* ee = (const float*)d_in[1];
    const float* ev = (const float*)d_in[2];
    const int*   er = (const int*)d_in[3];
    const int*   ec = (const int*)d_in[4];
    float* out = (float*)d_out;

    __half*       xh     = (__half*)d_ws;
    unsigned int* edges  = (unsigned int*)((char*)d_ws + 19200000);
    int*          cursor = (int*)((char*)d_ws + 28800000);
    __half*       WT     = (__half*)((char*)d_ws + 29400000);

    hipMemsetAsync(cursor, 0, (size_t)N_NODES * sizeof(int), stream);
    hist_kernel<<<N_EDGES / 256, 256, 0, stream>>>(er, cursor);
    scan_kernel<<<1, 1024, 0, stream>>>(cursor);
    build_csr_kernel<<<N_EDGES / 256, 256, 0, stream>>>(ev, er, ec, cursor, edges);

    init_x_kernel<<<(N_NODES * 16) / 256, 256, 0, stream>>>(ue, ee, out, xh);
    wt_kernel<<<52, 256, 0, stream>>>((const float*)d_in[5],  (const float*)d_in[7],
                                      (const float*)d_in[9],  (const float*)d_in[11],
                                      (const float*)d_in[13], (const float*)d_in[15], WT);

    const int GRID = N_NODES / 4;   // 37500

    // layer 0: DIN=64 DOUT=64, x at col 0, write col 64
    fused_layer_kernel<64, 64><<<GRID, 256, 0, stream>>>(cursor, edges, xh, out,
        WT, 0, 4096, (const float*)d_in[6], (const float*)d_in[8], 0, 64);
    conv_kernel<<<(N_NODES * 32) / 256, 256, 0, stream>>>(out + 64, xh, 64);

    // layer 1: DIN=64 DOUT=32, x at col 64, write col 128
    fused_layer_kernel<64, 32><<<GRID, 256, 0, stream>>>(cursor, edges, xh, out,
        WT, 8192, 10240, (const float*)d_in[10], (const float*)d_in[12], 64, 128);
    conv_kernel<<<(N_NODES * 16) / 256, 256, 0, stream>>>(out + 128, xh, 32);

    // layer 2: DIN=32 DOUT=16, x at col 128, write col 160
    fused_layer_kernel<32, 16><<<GRID, 256, 0, stream>>>(cursor, edges, xh, out,
        WT, 12288, 12800, (const float*)d_in[14], (const float*)d_in[16], 128, 160);
}

// Round 9
// 374.982 us; speedup vs baseline: 4.9632x; 1.9388x over previous
//
#include <hip/hip_runtime.h>
#include <hip/hip_fp16.h>

constexpr int N_USERS = 50000;
constexpr int N_ENT   = 100000;
constexpr int N_NODES = 150000;
constexpr int N_EDGES = 2400000;
constexpr int OUT_D   = 176;               // 64 + 64 + 32 + 16

constexpr int NBKT      = 293;             // coarse buckets = row >> 9
constexpr int P1_BLOCKS = 293;             // pass-1 blocks
constexpr int CHUNK     = 8192;            // edges per pass-1 block
constexpr int TBL       = NBKT * P1_BLOCKS;            // 85849
constexpr int SCAN_BLKS = (TBL + 1023) / 1024;         // 84

// ws layout (bytes):
//   tmp u64[2.4M] @0 (19.2MB)  -- later overwritten by xh fp16 [N][64]
//   edges u32 @19,200,000 (9.6MB)
//   cursor int[N] @28,800,000 (0.6MB)
//   table int[TBL] @29,400,000 (343KB) | bsum @30,000,000 (336B)
//   WT __half[13312] @30,100,000 (26.6KB)              = ~30.13MB

typedef _Float16 h2v __attribute__((ext_vector_type(2)));
union H2U { unsigned u; h2v v; };

__device__ inline float dot2(unsigned a, unsigned b, float c) {
    H2U x, y; x.u = a; y.u = b;
    return __builtin_amdgcn_fdot2(x.v, y.v, c, false);
}

// ---------------------------------------------------------------------------
// init: out[:,0:64) = concat(ue,ee);  xh = fp16 shadow [N][64]
// ---------------------------------------------------------------------------
__global__ __launch_bounds__(256) void init_x_kernel(const float* __restrict__ ue,
                                                     const float* __restrict__ ee,
                                                     float* __restrict__ out,
                                                     __half* __restrict__ xh) {
    int tid = blockIdx.x * 256 + threadIdx.x;    // N_NODES * 16 float4s
    int n = tid >> 4, q = tid & 15;
    const float* src = (n < N_USERS) ? ue + (size_t)n * 64
                                     : ee + (size_t)(n - N_USERS) * 64;
    float4 v = *(const float4*)(src + q * 4);
    *(float4*)(out + (size_t)n * OUT_D + q * 4) = v;
    union { __half2 h[2]; uint2 u; } pk;
    pk.h[0] = __floats2half2_rn(v.x, v.y);
    pk.h[1] = __floats2half2_rn(v.z, v.w);
    *(uint2*)(xh + (size_t)n * 64 + q * 4) = pk.u;
}

// fp32 slab column block -> dense fp16 shadow ([N][DIN]); 2 dims per thread
__global__ __launch_bounds__(256) void conv_kernel(const float* __restrict__ src,
                                                   __half* __restrict__ xh, int DIN) {
    int tid = blockIdx.x * 256 + threadIdx.x;    // N_NODES * DIN/2
    int n = tid / (DIN / 2), t = tid % (DIN / 2);
    float2 v = *(const float2*)(src + (size_t)n * OUT_D + 2 * t);
    *(__half2*)(xh + (size_t)n * DIN + 2 * t) = __floats2half2_rn(v.x, v.y);
}

// ---------------------------------------------------------------------------
// Weights, fp16, k-interleaved for coalesced per-o uint4 reads:
//   dest[base + (i/8)*DOUT*8 + o*8 + (i%8)] = W[i*DOUT + o]
// ---------------------------------------------------------------------------
__global__ __launch_bounds__(256) void wt_kernel(const float* __restrict__ Wg0,
                                                 const float* __restrict__ Wb0,
                                                 const float* __restrict__ Wg1,
                                                 const float* __restrict__ Wb1,
                                                 const float* __restrict__ Wg2,
                                                 const float* __restrict__ Wb2,
                                                 __half* __restrict__ WT) {
    int idx = blockIdx.x * 256 + threadIdx.x;   // 52*256 == 13312
    const float* src; int dout, base;
    if (idx < 8192)       { base = (idx < 4096) ? 0 : 4096;
                            src  = (idx < 4096) ? Wg0 : Wb0;  dout = 64; }
    else if (idx < 12288) { base = (idx < 10240) ? 8192 : 10240;
                            src  = (idx < 10240) ? Wg1 : Wb1; dout = 32; }
    else                  { base = (idx < 12800) ? 12288 : 12800;
                            src  = (idx < 12800) ? Wg2 : Wb2; dout = 16; }
    int r = idx - base;
    int i = r / dout, o = r % dout;
    int dest = base + (i / 8) * dout * 8 + o * 8 + (i % 8);
    WT[dest] = __float2half(src[r]);
}

// ---------------------------------------------------------------------------
// Two-level bucket sort replacing the atomic counting sort.
// Pass 1: partition by coarse bucket (row>>9) with per-block LDS hist.
// ---------------------------------------------------------------------------
__global__ __launch_bounds__(256) void histP1_kernel(const int* __restrict__ er,
                                                     int* __restrict__ table) {
    __shared__ int h[NBKT];
    for (int i = threadIdx.x; i < NBKT; i += 256) h[i] = 0;
    __syncthreads();
    int base = blockIdx.x * CHUNK;
    for (int i = threadIdx.x; i < CHUNK; i += 256) {
        int e = base + i;
        if (e < N_EDGES) atomicAdd(&h[er[e] >> 9], 1);
    }
    __syncthreads();
    for (int i = threadIdx.x; i < NBKT; i += 256)
        table[i * P1_BLOCKS + blockIdx.x] = h[i];
}

// 3-phase exclusive scan over n ints (A: block sums, B: scan sums, C: apply)
__global__ __launch_bounds__(1024) void scanA_kernel(const int* __restrict__ a,
                                                     int* __restrict__ bsum, int n) {
    __shared__ int wsum[16];
    int i = blockIdx.x * 1024 + threadIdx.x;
    int v = (i < n) ? a[i] : 0;
    #pragma unroll
    for (int off = 32; off; off >>= 1) v += __shfl_xor(v, off);
    int lane = threadIdx.x & 63, w = threadIdx.x >> 6;
    if (lane == 0) wsum[w] = v;
    __syncthreads();
    if (threadIdx.x == 0) {
        int t = 0;
        #pragma unroll
        for (int k = 0; k < 16; ++k) t += wsum[k];
        bsum[blockIdx.x] = t;
    }
}

__global__ __launch_bounds__(1024) void scanB_kernel(int* __restrict__ bsum, int n) {
    __shared__ int wtot[16];
    __shared__ int carry_s;
    int tid = threadIdx.x;
    int lane = tid & 63, w = tid >> 6;
    if (tid == 0) carry_s = 0;
    __syncthreads();
    for (int base = 0; base < n; base += 1024) {
        int i = base + tid;
        int v = (i < n) ? bsum[i] : 0;
        int incl = v;
        #pragma unroll
        for (int off = 1; off < 64; off <<= 1) {
            int t = __shfl_up(incl, off);
            if (lane >= off) incl += t;
        }
        if (lane == 63) wtot[w] = incl;
        __syncthreads();
        int woff = 0, total = 0;
        #pragma unroll
        for (int k = 0; k < 16; ++k) {
            int tk = wtot[k];
            if (k < w) woff += tk;
            total += tk;
        }
        if (i < n) bsum[i] = carry_s + woff + incl - v;
        __syncthreads();
        if (tid == 0) carry_s += total;
        __syncthreads();
    }
}

__global__ __launch_bounds__(1024) void scanC_kernel(int* __restrict__ a,
                                                     const int* __restrict__ bsum, int n) {
    __shared__ int wtot[16];
    int i = blockIdx.x * 1024 + threadIdx.x;
    int lane = threadIdx.x & 63, w = threadIdx.x >> 6;
    int v = (i < n) ? a[i] : 0;
    int incl = v;
    #pragma unroll
    for (int off = 1; off < 64; off <<= 1) {
        int t = __shfl_up(incl, off);
        if (lane >= off) incl += t;
    }
    if (lane == 63) wtot[w] = incl;
    __syncthreads();
    int woff = 0;
    #pragma unroll
    for (int k = 0; k < 16; ++k) if (k < w) woff += wtot[k];
    if (i < n) a[i] = bsum[blockIdx.x] + woff + incl - v;
}

// Pass-1 scatter: rec = (row&511)<<32 | col<<14 | val14 -> tmp (bucket-grouped)
__global__ __launch_bounds__(256) void scatterP1_kernel(const float* __restrict__ ev,
                                                        const int*   __restrict__ er,
                                                        const int*   __restrict__ ec,
                                                        const int*   __restrict__ table,
                                                        unsigned long long* __restrict__ tmp) {
    __shared__ int lcur[NBKT];
    for (int i = threadIdx.x; i < NBKT; i += 256)
        lcur[i] = table[i * P1_BLOCKS + blockIdx.x];
    __syncthreads();
    int base = blockIdx.x * CHUNK;
    for (int i = threadIdx.x; i < CHUNK; i += 256) {
        int e = base + i;
        if (e < N_EDGES) {
            int r = er[e], c = ec[e];
            int v14 = (int)(ev[e] * 16384.0f + 0.5f);
            v14 = v14 > 16383 ? 16383 : v14;
            int pos = atomicAdd(&lcur[r >> 9], 1);
            tmp[pos] = ((unsigned long long)(r & 511) << 32)
                     | ((unsigned)c << 14) | (unsigned)v14;
        }
    }
}

// Pass 2: per bucket: LDS hist over 512 rows -> LDS scan -> cursor[] +
// dense scatter of u32 payloads into the bucket's contiguous window.
__global__ __launch_bounds__(512) void pass2_kernel(const unsigned long long* __restrict__ tmp,
                                                    const int* __restrict__ table,
                                                    unsigned* __restrict__ edges,
                                                    int* __restrict__ cursor) {
    __shared__ int hcnt[512];
    __shared__ int sinc[512];
    __shared__ int lcur[512];
    int b = blockIdx.x;
    int tid = threadIdx.x;
    int eStart = table[b * P1_BLOCKS];
    int eEnd = (b + 1 < NBKT) ? table[(b + 1) * P1_BLOCKS] : N_EDGES;

    hcnt[tid] = 0;
    __syncthreads();
    for (int e = eStart + tid; e < eEnd; e += 512)
        atomicAdd(&hcnt[(int)(tmp[e] >> 32)], 1);
    __syncthreads();
    sinc[tid] = hcnt[tid];
    __syncthreads();
    #pragma unroll
    for (int off = 1; off < 512; off <<= 1) {
        int t = (tid >= off) ? sinc[tid - off] : 0;
        __syncthreads();
        sinc[tid] += t;
        __syncthreads();
    }
    int row = b * 512 + tid;
    if (row < N_NODES) cursor[row] = eStart + sinc[tid];   // inclusive end
    lcur[tid] = eStart + sinc[tid] - hcnt[tid];            // start
    __syncthreads();
    for (int e = eStart + tid; e < eEnd; e += 512) {
        unsigned long long rec = tmp[e];
        int pos = atomicAdd(&lcur[(int)(rec >> 32)], 1);
        edges[pos] = (unsigned)rec;
    }
}

// ---------------------------------------------------------------------------
// Fused layer (unchanged from R8). One wave per node.
// ---------------------------------------------------------------------------
template<int DIN, int DOUT>
__global__ __launch_bounds__(256, 4) void fused_layer_kernel(
        const int*          __restrict__ cursor,
        const unsigned int* __restrict__ edges,
        const __half*       __restrict__ xh,
        float* __restrict__ out,
        const __half* __restrict__ WT, int wgOff, int wbOff,
        const float* __restrict__ bgc, const float* __restrict__ bbi,
        int cin, int cout) {
    __shared__ unsigned ash[4][DIN / 2];
    __shared__ unsigned bsh[4][DIN / 2];

    int tid = threadIdx.x;
    int w = tid >> 6, lane = tid & 63;
    int n = blockIdx.x * 4 + w;

    constexpr int HP = DIN / 2;         // half2 per row
    constexpr int NE = 128 / DIN;       // edges per wave-gather (2 or 4)
    int g = lane / HP;                  // edge slot within gather instr
    int t = lane % HP;                  // dim-pair index

    int s = n ? cursor[n - 1] : 0;
    int e_end = cursor[n];

    float2 xv = make_float2(0.f, 0.f);
    if (lane < HP) xv = *(const float2*)(out + (size_t)n * OUT_D + cin + 2 * lane);

    const __half2* xr = (const __half2*)xh;
    float accx = 0.f, accy = 0.f;

    for (int e = s; e < e_end; e += 8 * NE) {
        unsigned ue[8];
        #pragma unroll
        for (int j = 0; j < 8; ++j) {
            int i = e + j * NE + g;
            unsigned raw = edges[i];     // unguarded: lands in ws (cursor area)
            ue[j] = (i < e_end) ? raw : 0u;
        }
        float vv[8]; float2 f[8];
        #pragma unroll
        for (int j = 0; j < 8; ++j) {
            unsigned c = ue[j] >> 14;
            vv[j] = (float)(ue[j] & 16383u) * (1.0f / 16384.0f);
            f[j] = __half22float2(xr[(size_t)c * HP + t]);
        }
        #pragma unroll
        for (int j = 0; j < 8; ++j) {
            accx += vv[j] * f[j].x;
            accy += vv[j] * f[j].y;
        }
    }
    #pragma unroll
    for (int m = 32; m >= HP; m >>= 1) {
        accx += __shfl_xor(accx, m);
        accy += __shfl_xor(accy, m);
    }

    if (lane < HP) {
        __half2 a2 = __floats2half2_rn(xv.x + accx, xv.y + accy);
        __half2 b2 = __floats2half2_rn(xv.x * accx, xv.y * accy);
        ash[w][lane] = *(unsigned*)&a2;
        bsh[w][lane] = *(unsigned*)&b2;
    }
    __syncthreads();

    float hres = 0.f;
    if constexpr (DOUT == DIN) {
        int o = lane;
        uint4 wg[DIN / 8], wb[DIN / 8];
        #pragma unroll
        for (int k = 0; k < DIN / 8; ++k) {
            wg[k] = *(const uint4*)(WT + wgOff + (size_t)(k * DOUT + o) * 8);
            wb[k] = *(const uint4*)(WT + wbOff + (size_t)(k * DOUT + o) * 8);
        }
        float ag = bgc[o], ab = bbi[o];
        #pragma unroll
        for (int k = 0; k < DIN / 8; ++k) {
            uint4 a4 = *(const uint4*)&ash[w][k * 4];
            uint4 b4 = *(const uint4*)&bsh[w][k * 4];
            ag = dot2(a4.x, wg[k].x, ag); ag = dot2(a4.y, wg[k].y, ag);
            ag = dot2(a4.z, wg[k].z, ag); ag = dot2(a4.w, wg[k].w, ag);
            ab = dot2(b4.x, wb[k].x, ab); ab = dot2(b4.y, wb[k].y, ab);
            ab = dot2(b4.z, wb[k].z, ab); ab = dot2(b4.w, wb[k].w, ab);
        }
        ag = ag > 0.f ? ag : 0.01f * ag;
        ab = ab > 0.f ? ab : 0.01f * ab;
        hres = ag + ab;
    } else {
        int o = lane & (DOUT - 1);
        bool gc = lane < DOUT;
        bool active = lane < 2 * DOUT;
        int woff2 = gc ? wgOff : wbOff;
        uint4 wr[DIN / 8];
        #pragma unroll
        for (int k = 0; k < DIN / 8; ++k)
            wr[k] = *(const uint4*)(WT + woff2 + (size_t)(k * DOUT + o) * 8);
        const unsigned* sp = gc ? &ash[w][0] : &bsh[w][0];
        float own = active ? (gc ? bgc[o] : bbi[o]) : 0.f;
        #pragma unroll
        for (int k = 0; k < DIN / 8; ++k) {
            uint4 s4 = *(const uint4*)(sp + k * 4);
            own = dot2(s4.x, wr[k].x, own); own = dot2(s4.y, wr[k].y, own);
            own = dot2(s4.z, wr[k].z, own); own = dot2(s4.w, wr[k].w, own);
        }
        own = own > 0.f ? own : 0.01f * own;
        float other = __shfl_xor(own, DOUT);
        hres = own + other;
    }

    float hq = (lane < DOUT) ? hres : 0.f;
    float ss = hq * hq;
    #pragma unroll
    for (int off = 32; off; off >>= 1) ss += __shfl_xor(ss, off);

    if (lane < DOUT) {
        float inv = 1.f / fmaxf(sqrtf(ss), 1e-12f);
        out[(size_t)n * OUT_D + cout + lane] = hres * inv;
    }
}

extern "C" void kernel_launch(void* const* d_in, const int* in_sizes, int n_in,
                              void* d_out, int out_size, void* d_ws, size_t ws_size,
                              hipStream_t stream) {
    const float* ue = (const float*)d_in[0];
    const float* ee = (const float*)d_in[1];
    const float* ev = (const float*)d_in[2];
    const int*   er = (const int*)d_in[3];
    const int*   ec = (const int*)d_in[4];
    float* out = (float*)d_out;

    unsigned long long* tmp    = (unsigned long long*)d_ws;     // dies at init_x
    __half*             xh     = (__half*)d_ws;
    unsigned int*       edges  = (unsigned int*)((char*)d_ws + 19200000);
    int*                cursor = (int*)((char*)d_ws + 28800000);
    int*                table  = (int*)((char*)d_ws + 29400000);
    int*                bsum   = (int*)((char*)d_ws + 30000000);
    __half*             WT     = (__half*)((char*)d_ws + 30100000);

    // ---- CSR via two-level bucket sort ----
    histP1_kernel<<<P1_BLOCKS, 256, 0, stream>>>(er, table);
    scanA_kernel<<<SCAN_BLKS, 1024, 0, stream>>>(table, bsum, TBL);
    scanB_kernel<<<1, 1024, 0, stream>>>(bsum, SCAN_BLKS);
    scanC_kernel<<<SCAN_BLKS, 1024, 0, stream>>>(table, bsum, TBL);
    scatterP1_kernel<<<P1_BLOCKS, 256, 0, stream>>>(ev, er, ec, table, tmp);
    pass2_kernel<<<NBKT, 512, 0, stream>>>(tmp, table, edges, cursor);

    // tmp dead; xh takes over the region
    init_x_kernel<<<(N_NODES * 16) / 256, 256, 0, stream>>>(ue, ee, out, xh);
    wt_kernel<<<52, 256, 0, stream>>>((const float*)d_in[5],  (const float*)d_in[7],
                                      (const float*)d_in[9],  (const float*)d_in[11],
                                      (const float*)d_in[13], (const float*)d_in[15], WT);

    const int GRID = N_NODES / 4;   // 37500

    fused_layer_kernel<64, 64><<<GRID, 256, 0, stream>>>(cursor, edges, xh, out,
        WT, 0, 4096, (const float*)d_in[6], (const float*)d_in[8], 0, 64);
    conv_kernel<<<(N_NODES * 32) / 256, 256, 0, stream>>>(out + 64, xh, 64);

    fused_layer_kernel<64, 32><<<GRID, 256, 0, stream>>>(cursor, edges, xh, out,
        WT, 8192, 10240, (const float*)d_in[10], (const float*)d_in[12], 64, 128);
    conv_kernel<<<(N_NODES * 16) / 256, 256, 0, stream>>>(out + 128, xh, 32);

    fused_layer_kernel<32, 16><<<GRID, 256, 0, stream>>>(cursor, edges, xh, out,
        WT, 12288, 12800, (const float*)d_in[14], (const float*)d_in[16], 128, 160);
}